// Round 1
// baseline (114.875 us; speedup 1.0000x reference)
//
#include <hip/hip_runtime.h>

#define IN_F 8192
#define OUT_F 8192
#define NT 256           // threads per block
#define VPT 8            // float4 loads per thread: 256*8*4 = 8192 floats per row

// ---------------------------------------------------------------------------
// ws layout: ws[0] (unsigned) = bitwise max of |W| (IEEE bits, valid since all
// finite non-negative patterns order like floats).
// ---------------------------------------------------------------------------

__global__ void zero_amax_kernel(unsigned* p) { *p = 0u; }

// Quantized term: sign(w) * clamp(floor(trunc(|w|*2^16)*inv_step + 0.5),1,15) * x
// Exactly equivalent to the jnp reference (all intermediates exact in fp32).
__device__ __forceinline__ float qterm(float w, float xv, float inv_step) {
    float v = truncf(fabsf(w) * 65536.0f);   // exact: *2^16 is an exponent shift
    float u = v * inv_step;                  // exact: inv_step is a power of two
    float q = floorf(u + 0.5f);              // round-half-up, exact (u mult of 2^-16, <16)
    q = fminf(fmaxf(q, 1.0f), 15.0f);
    q = (w == 0.0f) ? 0.0f : q;              // jnp.sign(0) == 0
    float t = q * xv;
    return __uint_as_float(__float_as_uint(t) ^ (__float_as_uint(w) & 0x80000000u));
}

// Pass 1: per-row speculative GEMV (assumes max_place == 20 -> step = 2^16,
// output scale 1.0) fused with the global abs-max reduction.
__global__ __launch_bounds__(NT) void gemv_spec_kernel(
    const float* __restrict__ W, const float* __restrict__ x,
    const float* __restrict__ bias, float* __restrict__ out,
    unsigned* __restrict__ amax) {
    const int row = blockIdx.x;
    const int t   = threadIdx.x;
    const float4* __restrict__ Wr = (const float4*)(W + (size_t)row * IN_F);
    const float4* __restrict__ x4 = (const float4*)x;
    const float inv_step = 1.0f / 65536.0f;  // speculative: step = 2^16

    float4 xv[VPT];
#pragma unroll
    for (int k = 0; k < VPT; ++k) xv[k] = x4[t + NT * k];

    float acc = 0.0f;
    unsigned um = 0u;
#pragma unroll
    for (int k = 0; k < VPT; ++k) {
        float4 wv = Wr[t + NT * k];
        um = max(um, __float_as_uint(wv.x) & 0x7fffffffu);
        um = max(um, __float_as_uint(wv.y) & 0x7fffffffu);
        um = max(um, __float_as_uint(wv.z) & 0x7fffffffu);
        um = max(um, __float_as_uint(wv.w) & 0x7fffffffu);
        acc += qterm(wv.x, xv[k].x, inv_step);
        acc += qterm(wv.y, xv[k].y, inv_step);
        acc += qterm(wv.z, xv[k].z, inv_step);
        acc += qterm(wv.w, xv[k].w, inv_step);
    }

    // wave-level reductions (wave64)
#pragma unroll
    for (int off = 32; off; off >>= 1) {
        acc += __shfl_down(acc, off);
        um = max(um, (unsigned)__shfl_down((int)um, off));
    }
    __shared__ float    ssum[NT / 64];
    __shared__ unsigned smax[NT / 64];
    const int lane = t & 63, wid = t >> 6;
    if (lane == 0) { ssum[wid] = acc; smax[wid] = um; }
    __syncthreads();
    if (t == 0) {
        float total = ssum[0] + ssum[1] + ssum[2] + ssum[3];
        unsigned bm = max(max(smax[0], smax[1]), max(smax[2], smax[3]));
        out[row] = total + bias[row];        // oscale = 2^(20-20) = 1
        atomicMax(amax, bm);                 // device-scope by default
    }
}

// Pass 2: verify speculation; if max_place != 20 (never for this input, but
// required for correctness in general), redo the GEMV with the true step.
__global__ __launch_bounds__(NT) void gemv_fix_kernel(
    const float* __restrict__ W, const float* __restrict__ x,
    const float* __restrict__ bias, float* __restrict__ out,
    const unsigned* __restrict__ amax) {
    const float am = __uint_as_float(*amax);          // max |W|
    const unsigned mi = (unsigned)truncf(am * 65536.0f);  // m = trunc(scale*max|W|)
    int mp;                                           // max_place
    if (mi <= 1u) mp = 1;
    else          mp = 33 - __clz((int)(mi - 1u));    // ceil(log2(mi)) + 1
    if (mp < 4) mp = 4;
    if (mp == 20) return;                             // speculation correct: done

    const float inv_step = exp2f((float)(4 - mp));    // 1/step
    const float oscale   = exp2f((float)(mp - 20));   // step/2^16

    const int row = blockIdx.x;
    const int t   = threadIdx.x;
    const float4* __restrict__ Wr = (const float4*)(W + (size_t)row * IN_F);
    const float4* __restrict__ x4 = (const float4*)x;

    float4 xv[VPT];
#pragma unroll
    for (int k = 0; k < VPT; ++k) xv[k] = x4[t + NT * k];

    float acc = 0.0f;
#pragma unroll
    for (int k = 0; k < VPT; ++k) {
        float4 wv = Wr[t + NT * k];
        acc += qterm(wv.x, xv[k].x, inv_step);
        acc += qterm(wv.y, xv[k].y, inv_step);
        acc += qterm(wv.z, xv[k].z, inv_step);
        acc += qterm(wv.w, xv[k].w, inv_step);
    }

#pragma unroll
    for (int off = 32; off; off >>= 1) acc += __shfl_down(acc, off);
    __shared__ float ssum[NT / 64];
    const int lane = t & 63, wid = t >> 6;
    if (lane == 0) ssum[wid] = acc;
    __syncthreads();
    if (t == 0)
        out[row] = (ssum[0] + ssum[1] + ssum[2] + ssum[3]) * oscale + bias[row];
}

extern "C" void kernel_launch(void* const* d_in, const int* in_sizes, int n_in,
                              void* d_out, int out_size, void* d_ws, size_t ws_size,
                              hipStream_t stream) {
    const float* x    = (const float*)d_in[0];   // input  [8192]
    const float* W    = (const float*)d_in[1];   // weight [8192, 8192]
    const float* bias = (const float*)d_in[2];   // bias   [8192]
    float* out = (float*)d_out;
    unsigned* amax = (unsigned*)d_ws;

    zero_amax_kernel<<<1, 1, 0, stream>>>(amax);
    gemv_spec_kernel<<<OUT_F, NT, 0, stream>>>(W, x, bias, out, amax);
    gemv_fix_kernel<<<OUT_F, NT, 0, stream>>>(W, x, bias, out, amax);
}

// Round 2
// 57.456 us; speedup vs baseline: 1.9993x; 1.9993x over previous
//
#include <hip/hip_runtime.h>

#define IN_F 8192
#define OUT_F 8192
#define NT 256               // threads per block
#define VPT 8                // float4 loads per thread per row (256*8*4 = 8192)
#define RPB 8                // rows per block
#define NBLK (OUT_F / RPB)   // 1024 blocks -> 4 blocks/CU, one generation

typedef float f32x4 __attribute__((ext_vector_type(4)));

// ws[0] (unsigned) = bitwise max over v = trunc(|w| * 2^16)  (>=0 floats order as uints)
__global__ void zero_amax_kernel(unsigned* p) { *p = 0u; }

// term = sign(w) * clamp(floor(trunc(|w|*2^16)*inv_step + 0.5), 1, 15) * xv
// exact fp32 reproduction of the jnp reference; also tracks vmax = max(v).
__device__ __forceinline__ float qterm(float w, float xv, float inv_step, float& vmax) {
    float v = truncf(fabsf(w) * 65536.0f);   // exact (exponent shift + trunc)
    vmax = fmaxf(vmax, v);
    float u = v * inv_step;                  // exact (power-of-two scale)
    float q = floorf(u + 0.5f);              // exact round-half-up (u mult of 2^-16, <16)
    q = fminf(fmaxf(q, 1.0f), 15.0f);        // med3
    q = (w == 0.0f) ? 0.0f : q;              // sign(0) == 0
    float t = q * xv;
    return __uint_as_float(__float_as_uint(t) ^ (__float_as_uint(w) & 0x80000000u));
}

// Pass 1: speculative GEMV (step = 2^16 <=> max_place == 20) fused with abs-max.
__global__ __launch_bounds__(NT, 4) void gemv_spec_kernel(
    const float* __restrict__ W, const float* __restrict__ x,
    const float* __restrict__ bias, float* __restrict__ out,
    unsigned* __restrict__ amax) {
    const int t = threadIdx.x;
    const int lane = t & 63, wid = t >> 6;
    const size_t row0 = (size_t)blockIdx.x * RPB;
    const f32x4* __restrict__ x4 = (const f32x4*)x;
    const float inv_step = 1.0f / 65536.0f;

    f32x4 xv[VPT];
#pragma unroll
    for (int k = 0; k < VPT; ++k) xv[k] = x4[t + NT * k];

    __shared__ float    ssum[RPB][NT / 64];
    __shared__ unsigned smax[NT / 64];
    float vmax = 0.0f;

#pragma unroll 2
    for (int j = 0; j < RPB; ++j) {
        const f32x4* __restrict__ Wr = (const f32x4*)(W + (row0 + j) * IN_F);
        f32x4 wv[VPT];
#pragma unroll
        for (int k = 0; k < VPT; ++k) wv[k] = __builtin_nontemporal_load(Wr + t + NT * k);
        float a = 0.0f;
#pragma unroll
        for (int k = 0; k < VPT; ++k) {
            a += qterm(wv[k].x, xv[k].x, inv_step, vmax);
            a += qterm(wv[k].y, xv[k].y, inv_step, vmax);
            a += qterm(wv[k].z, xv[k].z, inv_step, vmax);
            a += qterm(wv[k].w, xv[k].w, inv_step, vmax);
        }
#pragma unroll
        for (int off = 32; off; off >>= 1) a += __shfl_down(a, off);
        if (lane == 0) ssum[j][wid] = a;
    }

#pragma unroll
    for (int off = 32; off; off >>= 1)
        vmax = fmaxf(vmax, __shfl_down(vmax, off));
    if (lane == 0) smax[wid] = __float_as_uint(vmax);
    __syncthreads();

    if (t < RPB) {
        float s = ssum[t][0] + ssum[t][1] + ssum[t][2] + ssum[t][3];
        out[row0 + t] = s + bias[row0 + t];      // oscale = 2^(20-20) = 1
    }
    if (t == 0) {
        unsigned bm = max(max(smax[0], smax[1]), max(smax[2], smax[3]));
        atomicMax(amax, bm);                     // device scope
    }
}

// Pass 2: verify speculation; redo with true step if max_place != 20
// (never taken for this input, required for general correctness).
__global__ __launch_bounds__(NT, 4) void gemv_fix_kernel(
    const float* __restrict__ W, const float* __restrict__ x,
    const float* __restrict__ bias, float* __restrict__ out,
    const unsigned* __restrict__ amax) {
    const float am = __uint_as_float(*amax);     // m = trunc(2^16 * max|W|), integer-valued
    const unsigned mi = (unsigned)am;
    int mp;                                      // max_place = max(ceil(log2(m))+1, 4)
    if (mi <= 1u) mp = 1;
    else          mp = 33 - __clz((int)(mi - 1u));
    if (mp < 4) mp = 4;
    if (mp == 20) return;                        // speculation was correct

    const float inv_step = __builtin_ldexpf(1.0f, 4 - mp);   // 1/step (exact)
    const float oscale   = __builtin_ldexpf(1.0f, mp - 20);  // step/2^16 (exact)

    const int t = threadIdx.x;
    const int lane = t & 63, wid = t >> 6;
    const size_t row0 = (size_t)blockIdx.x * RPB;
    const f32x4* __restrict__ x4 = (const f32x4*)x;

    f32x4 xv[VPT];
#pragma unroll
    for (int k = 0; k < VPT; ++k) xv[k] = x4[t + NT * k];

    __shared__ float ssum[RPB][NT / 64];
    float dummy = 0.0f;

#pragma unroll 2
    for (int j = 0; j < RPB; ++j) {
        const f32x4* __restrict__ Wr = (const f32x4*)(W + (row0 + j) * IN_F);
        f32x4 wv[VPT];
#pragma unroll
        for (int k = 0; k < VPT; ++k) wv[k] = __builtin_nontemporal_load(Wr + t + NT * k);
        float a = 0.0f;
#pragma unroll
        for (int k = 0; k < VPT; ++k) {
            a += qterm(wv[k].x, xv[k].x, inv_step, dummy);
            a += qterm(wv[k].y, xv[k].y, inv_step, dummy);
            a += qterm(wv[k].z, xv[k].z, inv_step, dummy);
            a += qterm(wv[k].w, xv[k].w, inv_step, dummy);
        }
#pragma unroll
        for (int off = 32; off; off >>= 1) a += __shfl_down(a, off);
        if (lane == 0) ssum[j][wid] = a;
    }
    __syncthreads();

    if (t < RPB) {
        float s = ssum[t][0] + ssum[t][1] + ssum[t][2] + ssum[t][3];
        out[row0 + t] = s * oscale + bias[row0 + t];
    }
}

extern "C" void kernel_launch(void* const* d_in, const int* in_sizes, int n_in,
                              void* d_out, int out_size, void* d_ws, size_t ws_size,
                              hipStream_t stream) {
    const float* x    = (const float*)d_in[0];   // input  [8192]
    const float* W    = (const float*)d_in[1];   // weight [8192, 8192]
    const float* bias = (const float*)d_in[2];   // bias   [8192]
    float* out = (float*)d_out;
    unsigned* amax = (unsigned*)d_ws;

    zero_amax_kernel<<<1, 1, 0, stream>>>(amax);
    gemv_spec_kernel<<<NBLK, NT, 0, stream>>>(W, x, bias, out, amax);
    gemv_fix_kernel<<<NBLK, NT, 0, stream>>>(W, x, bias, out, amax);
}